// Round 6
// baseline (193.459 us; speedup 1.0000x reference)
//
#include <hip/hip_runtime.h>
#include <math.h>

#define B_   128
#define T_   50
#define MI_  32
#define E_   128
#define EW_  16
#define D_   144
#define G_   432        // 3*D
#define N_   (B_*T_)    // 6400

// ---------------------------------------------------------------------------
// K1: basket embedding v2 — parallel gather (unchanged, known good).
// ---------------------------------------------------------------------------
__global__ __launch_bounds__(256) void embed_kernel(
    const int* __restrict__ x,            // [N_][33]
    const float* __restrict__ encode_w,   // [100000][128]  (row 0 == 0)
    const float* __restrict__ wchange_w,  // [2][16]
    float* __restrict__ seq)              // [N_][144]
{
    int n = blockIdx.x;
    int tid = threadIdx.x;
    int i = tid >> 3;        // item 0..31
    int j = tid & 7;         // col chunk [16j, 16j+16)

    __shared__ int xi[33];
    __shared__ __align__(16) float part[32 * 132];  // stride 132 words
    __shared__ float cntf[32];

    if (tid < 33) xi[tid] = x[n * 33 + tid];
    __syncthreads();

    int it = xi[i];
    const float* row = &encode_w[(size_t)it * E_];
    float4 v0 = *(const float4*)&row[16 * j + 0];
    float4 v1 = *(const float4*)&row[16 * j + 4];
    float4 v2 = *(const float4*)&row[16 * j + 8];
    float4 v3 = *(const float4*)&row[16 * j + 12];

    float* p = &part[i * 132 + 16 * j];
    *(float4*)&p[0]  = v0;
    *(float4*)&p[4]  = v1;
    *(float4*)&p[8]  = v2;
    *(float4*)&p[12] = v3;
    if (j == 0) cntf[i] = (it != 0) ? 1.f : 0.f;
    __syncthreads();

    if (tid < E_) {
        int c = tid;
        float s = 0.f, cn = 0.f;
        #pragma unroll
        for (int k = 0; k < 32; ++k) {
            s  += part[k * 132 + c];   // 2-way bank aliasing: free
            cn += cntf[k];             // broadcast: free
        }
        seq[n * D_ + c] = s / fmaxf(cn, 1.f);
    } else if (tid < E_ + EW_) {
        int c = tid - E_;
        seq[n * D_ + E_ + c] = wchange_w[xi[32] * EW_ + c];
    }
}

// ---------------------------------------------------------------------------
// DPP butterfly add across 8 lanes (shared by K2/K3/K4).
// ---------------------------------------------------------------------------
template<int CTRL>
__device__ __forceinline__ float dpp_xor_add(float x) {
    int y = __builtin_amdgcn_mov_dpp(__float_as_int(x), CTRL, 0xF, 0xF, true);
    return x + __int_as_float(y);
}
#define DPP_RED3(v) \
    v = dpp_xor_add<0xB1>(v); v = dpp_xor_add<0x4E>(v); v = dpp_xor_add<0x141>(v);

// ---------------------------------------------------------------------------
// K2 v3: persistent weights-stationary MATVEC (replaces the tiled GEMM).
// Rationale: K2 ran ~8x off its issue floor — 2.7 blocks/CU of a
// stage->barrier->compute schedule is stall-dominated, and both the 128x128
// tile (round 4) and LDS double-buffering (round 5) were neutral-to-worse.
// This is the GRU's proven structure applied to 6400 independent matvecs:
// 256 blocks (exactly 1/CU, 25 n each), 576 threads, w_ih resident in
// w[6][20] VGPRs (identical mapping/known no-spill), all 25 seq rows
// preloaded to LDS (16KB).  Main loop: ZERO barriers, zero global loads —
// 5 broadcast ds_read_b128 + 120 FMA + 18 DPP per n; stores fire-and-forget.
// ---------------------------------------------------------------------------
__global__ __launch_bounds__(576) void gi_matvec_kernel(
    const float* __restrict__ seq,    // [N_][144]
    const float* __restrict__ w_ih,   // [432][144]
    const float* __restrict__ b_ih,   // [432]
    float* __restrict__ gi)           // [N_][432]
{
    int n0 = blockIdx.x * 25;         // 256 blocks x 25 rows
    int tid = threadIdx.x;
    int g = tid >> 3;                 // 0..71 -> rows 6g..6g+5
    int s = tid & 7;                  // k-chunk [20s, 20s+20)
    int k0 = s * 20;

    __shared__ __align__(16) float sq[25 * 160];   // 25 rows, stride 160

    // preload: zero pads then 25x144 floats as float4
    {
        float4* d4 = (float4*)sq;
        const float4* s4 = (const float4*)(seq + (size_t)n0 * D_);
        for (int idx = tid; idx < 100; idx += 576) {       // pads [144..160)
            int i = idx >> 2, p = idx & 3;
            d4[i * 40 + 36 + p] = make_float4(0.f, 0.f, 0.f, 0.f);
        }
        for (int idx = tid; idx < 900; idx += 576) {       // 25*36 f4 data
            int i = idx / 36, q = idx - i * 36;
            d4[i * 40 + q] = s4[i * 36 + q];
        }
    }

    // weights-stationary: rows 6g..6g+5, k-chunk k0..k0+20 (zero-padded)
    float w[6][20];
    #pragma unroll
    for (int r = 0; r < 6; ++r) {
        const float* wrow = &w_ih[(size_t)(6 * g + r) * D_];
        #pragma unroll
        for (int q = 0; q < 5; ++q) {
            int k = k0 + 4 * q;
            float4 t = make_float4(0.f, 0.f, 0.f, 0.f);
            if (k < D_) t = *(const float4*)&wrow[k];
            w[r][4 * q + 0] = t.x;
            w[r][4 * q + 1] = t.y;
            w[r][4 * q + 2] = t.z;
            w[r][4 * q + 3] = t.w;
        }
    }
    float bias = (s < 6) ? b_ih[6 * g + s] : 0.f;
    __syncthreads();                  // the ONLY barrier

    const float* hp = sq + k0;
    float* gp = gi + (size_t)n0 * G_ + 6 * g + s;
    for (int i = 0; i < 25; ++i) {
        float hv[20];
        #pragma unroll
        for (int q = 0; q < 5; ++q) {
            float4 t4 = *(const float4*)&hp[i * 160 + 4 * q];
            hv[4 * q + 0] = t4.x;
            hv[4 * q + 1] = t4.y;
            hv[4 * q + 2] = t4.z;
            hv[4 * q + 3] = t4.w;
        }
        float a0 = 0.f, a1 = 0.f, a2 = 0.f, a3 = 0.f, a4 = 0.f, a5 = 0.f;
        #pragma unroll
        for (int kk = 0; kk < 20; ++kk) {
            float hk = hv[kk];
            a0 = fmaf(w[0][kk], hk, a0);
            a1 = fmaf(w[1][kk], hk, a1);
            a2 = fmaf(w[2][kk], hk, a2);
            a3 = fmaf(w[3][kk], hk, a3);
            a4 = fmaf(w[4][kk], hk, a4);
            a5 = fmaf(w[5][kk], hk, a5);
        }
        DPP_RED3(a0); DPP_RED3(a1); DPP_RED3(a2);
        DPP_RED3(a3); DPP_RED3(a4); DPP_RED3(a5);
        float myacc = a0;
        if (s == 1) myacc = a1;
        if (s == 2) myacc = a2;
        if (s == 3) myacc = a3;
        if (s == 4) myacc = a4;
        if (s == 5) myacc = a5;
        if (s < 6) gp[(size_t)i * G_] = myacc + bias;   // fire-and-forget
    }
}

// ---------------------------------------------------------------------------
// K4 v2: same persistent matvec for dyn = hseq @ fc_w^T + fc_b (128 rows).
// 512 threads: group g=tid>>3 (0..63) owns rows {2g,2g+1}; w[2][20].
// ---------------------------------------------------------------------------
__global__ __launch_bounds__(512) void fc_matvec_kernel(
    const float* __restrict__ hseq,   // [N_][144]
    const float* __restrict__ fc_w,   // [128][144]
    const float* __restrict__ fc_b,   // [128]
    float* __restrict__ dyn)          // [N_][128]
{
    int n0 = blockIdx.x * 25;
    int tid = threadIdx.x;
    int g = tid >> 3;                 // 0..63 -> rows 2g, 2g+1
    int s = tid & 7;
    int k0 = s * 20;

    __shared__ __align__(16) float sq[25 * 160];

    {
        float4* d4 = (float4*)sq;
        const float4* s4 = (const float4*)(hseq + (size_t)n0 * D_);
        for (int idx = tid; idx < 100; idx += 512) {
            int i = idx >> 2, p = idx & 3;
            d4[i * 40 + 36 + p] = make_float4(0.f, 0.f, 0.f, 0.f);
        }
        for (int idx = tid; idx < 900; idx += 512) {
            int i = idx / 36, q = idx - i * 36;
            d4[i * 40 + q] = s4[i * 36 + q];
        }
    }

    float w[2][20];
    #pragma unroll
    for (int r = 0; r < 2; ++r) {
        const float* wrow = &fc_w[(size_t)(2 * g + r) * D_];
        #pragma unroll
        for (int q = 0; q < 5; ++q) {
            int k = k0 + 4 * q;
            float4 t = make_float4(0.f, 0.f, 0.f, 0.f);
            if (k < D_) t = *(const float4*)&wrow[k];
            w[r][4 * q + 0] = t.x;
            w[r][4 * q + 1] = t.y;
            w[r][4 * q + 2] = t.z;
            w[r][4 * q + 3] = t.w;
        }
    }
    float bias = (s < 2) ? fc_b[2 * g + s] : 0.f;
    __syncthreads();

    const float* hp = sq + k0;
    float* gp = dyn + (size_t)n0 * E_ + 2 * g + s;
    for (int i = 0; i < 25; ++i) {
        float hv[20];
        #pragma unroll
        for (int q = 0; q < 5; ++q) {
            float4 t4 = *(const float4*)&hp[i * 160 + 4 * q];
            hv[4 * q + 0] = t4.x;
            hv[4 * q + 1] = t4.y;
            hv[4 * q + 2] = t4.z;
            hv[4 * q + 3] = t4.w;
        }
        float f0 = 0.f, f1 = 0.f;
        #pragma unroll
        for (int kk = 0; kk < 20; ++kk) {
            float hk = hv[kk];
            f0 = fmaf(w[0][kk], hk, f0);
            f1 = fmaf(w[1][kk], hk, f1);
        }
        DPP_RED3(f0); DPP_RED3(f1);
        float myacc = (s == 0) ? f0 : f1;
        if (s < 2) gp[(size_t)i * E_] = myacc + bias;
    }
}

// ---------------------------------------------------------------------------
// K3: GRU v6 (best measured: 52.9us) — v3 structure + 1-step-ahead gi
// pipeline.  Locked-in lessons: elementwise dense in tid<144 (v4);
// no extra resident weight arrays (v5 spill disaster); plain __syncthreads
// (bar_nodrain null, round 4); dbuf null (round 5).
// ---------------------------------------------------------------------------
__global__ __launch_bounds__(576) void gru_kernel(
    const float* __restrict__ gi,     // [N_][432]
    const float* __restrict__ w_hh,   // [432][144]
    const float* __restrict__ b_hh,   // [432]
    const float* __restrict__ h0,     // [128][144]
    float* __restrict__ hseq,         // [N_][144]
    float* __restrict__ hlast)        // [128][144]
{
    int b = blockIdx.x;
    int tid = threadIdx.x;
    int g = tid >> 3;       // 0..71  -> rows 6g..6g+5
    int s = tid & 7;        // k-chunk [20s, 20s+20)
    int k0 = s * 20;

    __shared__ __align__(16) float h[160];   // k-padded; [144..159] stay 0
    __shared__ float gh[G_];

    float w[6][20];
    #pragma unroll
    for (int r = 0; r < 6; ++r) {
        const float* wrow = &w_hh[(size_t)(6 * g + r) * D_];
        #pragma unroll
        for (int q = 0; q < 5; ++q) {
            int k = k0 + 4 * q;
            float4 t = make_float4(0.f, 0.f, 0.f, 0.f);
            if (k < D_) t = *(const float4*)&wrow[k];   // k<=140, safe
            w[r][4 * q + 0] = t.x;
            w[r][4 * q + 1] = t.y;
            w[r][4 * q + 2] = t.z;
            w[r][4 * q + 3] = t.w;
        }
    }
    float bias = (s < 6) ? b_hh[6 * g + s] : 0.f;

    if (tid < 160) h[tid] = (tid < D_) ? h0[b * D_ + tid] : 0.f;
    __syncthreads();

    // gi pipeline: registers hold step t's values at top of iteration t
    float gir = 0.f, giz = 0.f, gin = 0.f;
    if (tid < D_) {
        const float* gp = &gi[(size_t)(b * T_) * G_];
        gir = gp[tid];
        giz = gp[D_ + tid];
        gin = gp[2 * D_ + tid];
    }

    for (int t = 0; t < T_; ++t) {
        int n = b * T_ + t;

        float girU = gir, gizU = giz, ginU = gin;
        if (tid < D_ && t + 1 < T_) {
            const float* gp = &gi[(size_t)(n + 1) * G_];
            gir = gp[tid];
            giz = gp[D_ + tid];
            gin = gp[2 * D_ + tid];
        }

        float hv[20];
        #pragma unroll
        for (int q = 0; q < 5; ++q) {
            float4 t4 = *(const float4*)&h[k0 + 4 * q];
            hv[4 * q + 0] = t4.x;
            hv[4 * q + 1] = t4.y;
            hv[4 * q + 2] = t4.z;
            hv[4 * q + 3] = t4.w;
        }

        float a0 = 0.f, a1 = 0.f, a2 = 0.f, a3 = 0.f, a4 = 0.f, a5 = 0.f;
        #pragma unroll
        for (int kk = 0; kk < 20; ++kk) {
            float hk = hv[kk];
            a0 = fmaf(w[0][kk], hk, a0);
            a1 = fmaf(w[1][kk], hk, a1);
            a2 = fmaf(w[2][kk], hk, a2);
            a3 = fmaf(w[3][kk], hk, a3);
            a4 = fmaf(w[4][kk], hk, a4);
            a5 = fmaf(w[5][kk], hk, a5);
        }

        DPP_RED3(a0); DPP_RED3(a1); DPP_RED3(a2);
        DPP_RED3(a3); DPP_RED3(a4); DPP_RED3(a5);

        float myacc = a0;
        if (s == 1) myacc = a1;
        if (s == 2) myacc = a2;
        if (s == 3) myacc = a3;
        if (s == 4) myacc = a4;
        if (s == 5) myacc = a5;
        if (s < 6) gh[6 * g + s] = myacc + bias;
        __syncthreads();

        if (tid < D_) {
            float r = 1.f / (1.f + __expf(-(girU + gh[tid])));
            float z = 1.f / (1.f + __expf(-(gizU + gh[D_ + tid])));
            float narg = ginU + r * gh[2 * D_ + tid];
            narg = fminf(fmaxf(narg, -15.f), 15.f);
            float e2 = __expf(-2.f * narg);
            float nn = (1.f - e2) / (1.f + e2);
            float hn = (1.f - z) * nn + z * h[tid];
            hseq[(size_t)n * D_ + tid] = hn;
            h[tid] = hn;
        }
        __syncthreads();
    }

    if (tid < D_) hlast[b * D_ + tid] = h[tid];
}

// ---------------------------------------------------------------------------
extern "C" void kernel_launch(void* const* d_in, const int* in_sizes, int n_in,
                              void* d_out, int out_size, void* d_ws, size_t ws_size,
                              hipStream_t stream)
{
    const int*   x         = (const int*)d_in[0];
    // d_in[1] = lengths (unused by the reference computation)
    const float* hidden    = (const float*)d_in[2];
    const float* encode_w  = (const float*)d_in[3];
    const float* wchange_w = (const float*)d_in[4];
    const float* w_ih      = (const float*)d_in[5];
    const float* w_hh      = (const float*)d_in[6];
    const float* b_ih      = (const float*)d_in[7];
    const float* b_hh      = (const float*)d_in[8];
    const float* fc_w      = (const float*)d_in[9];
    const float* fc_b      = (const float*)d_in[10];

    float* out = (float*)d_out;              // [N_][128] then [128][144]
    float* ws  = (float*)d_ws;
    float* seq  = ws;                        //   921600 floats
    float* gi   = ws + 921600;               //  2764800 floats
    float* hseq = ws + 921600 + 2764800;     //   921600 floats  (18.4 MB total)

    // K1: embedding (parallel gather v2)
    embed_kernel<<<N_, 256, 0, stream>>>(x, encode_w, wchange_w, seq);

    // K2: gi = seq @ w_ih^T + b_ih — persistent weights-stationary matvec
    gi_matvec_kernel<<<256, 576, 0, stream>>>(seq, w_ih, b_ih, gi);

    // K3: GRU over T=50 (v6: best measured)
    gru_kernel<<<B_, 576, 0, stream>>>(gi, w_hh, b_hh, hidden, hseq,
                                       out + (size_t)N_ * E_);

    // K4: dynamic_user = hseq @ fc_w^T + fc_b — persistent matvec
    fc_matvec_kernel<<<256, 512, 0, stream>>>(hseq, fc_w, fc_b, out);
}